// Round 18
// baseline (175.647 us; speedup 1.0000x reference)
//
#include <hip/hip_runtime.h>
#include <hip/hip_bf16.h>

// Problem constants (from reference)
#define E_EDGES 262144
#define B_SAMP  1024
#define L_SEQ   10
#define T_SEG   (B_SAMP * L_SEQ)   // 10240 segments
#define H_DIM   128
#define N_ENT_C 40000
#define N_REL_C 256

typedef __attribute__((ext_vector_type(8))) short short8;   // 8 bf16 (4 VGPRs)
typedef __attribute__((ext_vector_type(4))) float f32x4;

__device__ __forceinline__ float b2f(__hip_bfloat16 x) { return __bfloat162float(x); }
__device__ __forceinline__ unsigned short f2bu(float x) {
    return __bfloat16_as_ushort(__float2bfloat16(x));
}

// Float load with runtime-detected storage (bf16 vs float32).
__device__ __forceinline__ float loadF(const void* base, int idx, int isB16) {
    if (isB16) return b2f(((const __hip_bfloat16*)base)[idx]);
    return ((const float*)base)[idx];
}
// Integer load with runtime-detected width (int64 vs int32).
__device__ __forceinline__ int loadI(const void* base, int idx, int is64) {
    if (is64) return (int)(((const long long*)base)[idx]);
    return ((const int*)base)[idx];
}

// Per-block dtype detection (cheap, deterministic; no cross-block deps).
__device__ __forceinline__ void detect_dtypes(const void* att_raw,
                                              const void* sid_raw,
                                              int tid, int nthr,
                                              int& isB, int& i64)
{
    __shared__ int cF, cI;
    if (tid == 0) { cF = 0; cI = 0; }
    __syncthreads();
    const unsigned short* pa = (const unsigned short*)att_raw;
    int c = 0;
    for (int i = tid; i < 2048; i += nthr) if (pa[i] <= 0x3F80u) c++;
    if (c) atomicAdd(&cF, c);
    const int* ps = (const int*)sid_raw;
    c = 0;
    for (int i = tid; i < 512; i += nthr) if (ps[2 * i + 1] == 0) c++;
    if (c) atomicAdd(&cI, c);
    __syncthreads();
    isB = (cF >= 1900) ? 1 : 0;
    i64 = (cI >= 256) ? 1 : 0;
}

// ---------------------------------------------------------------------------
// K_A (r17 layout): all prep in one launch, blocks fully independent.
//  bid [0,256):   bf16 weight tables, n-major k-contig for MFMA B-frags.
//  bid [256,385): ab3 — ONE j per block (2x parallelism; bitwise-identical).
//  bid 385:       global scalar vectors + dtype flags.
//  bid [386,642): edge-meta pass + STARTS SCATTER (replaces 41 binary-search
//                 blocks; exact lower_bound semantics, bitwise-identical).
//                 metaE[i] = uint4{att_f32_bits, ent*128, rel*128, j*128}.
// ---------------------------------------------------------------------------
__global__ void __launch_bounds__(256)
ka_prep(const void* __restrict__ W3w, const void* __restrict__ W4w,
        const void* __restrict__ W1w, const void* __restrict__ W1b,
        const void* __restrict__ W3b, const void* __restrict__ W4b,
        const void* __restrict__ seg_ids,
        const void* __restrict__ nbr_ent, const void* __restrict__ nbr_rel,
        const void* __restrict__ att_raw, const void* __restrict__ sid_raw,
        unsigned short* __restrict__ wctEb, unsigned short* __restrict__ wctRb,
        unsigned int* __restrict__ ab3p, int* __restrict__ starts,
        uint4* __restrict__ metaE,
        float* __restrict__ W1w_f, float* __restrict__ W1b_f,
        float* __restrict__ W3b_f, float* __restrict__ W4b_f,
        int* __restrict__ flag, int* __restrict__ iflag)
{
    const int bid = blockIdx.x, tid = threadIdx.x;
    int isB, i64;
    detect_dtypes(att_raw, sid_raw, tid, 256, isB, i64);

    if (bid < 256) {
        int gid = bid * 256 + tid;
        if (gid < 32768) {
            int n = gid >> 7, k = gid & 127;
            float v = (n < 128) ? loadF(W3w, n * 384 + 128 + k, isB)
                                : loadF(W4w, (n - 128) * 256 + k, isB);
            wctEb[gid] = f2bu(v);
        } else {
            int j = gid - 32768;
            int n = j >> 7, k = j & 127;
            float v = (n < 128) ? loadF(W3w, n * 384 + 256 + k, isB)
                                : loadF(W4w, (n - 128) * 256 + 128 + k, isB);
            wctRb[j] = f2bu(v);
        }
        return;
    }

    // All remaining blocks need the sorted breakpoints: derive locally.
    // thr_k = -b1k/w1k if in (0,1) else sentinel 2.0; rank-sort in LDS.
    __shared__ float w1s[128], b1s[128], srt[128];
    __shared__ int nInS;
    if (tid < 128) {
        float w = loadF(W1w, tid, isB);
        float b = loadF(W1b, tid, isB);
        w1s[tid] = w; b1s[tid] = b;
    }
    __syncthreads();
    if (tid < 128) {
        float w = w1s[tid], b = b1s[tid];
        float t = 2.0f;
        if (w != 0.0f) {
            float tt = -b / w;
            if (tt > 0.0f && tt < 1.0f) t = tt;
        }
        srt[tid] = t;   // temporarily unsorted
    }
    __syncthreads();
    float myt = 0.0f; int rank = 0, n = 0;
    if (tid < 128) {
        myt = srt[tid];
        for (int j = 0; j < 128; ++j) {
            float v = srt[j];
            rank += (v < myt) || (v == myt && j < tid);
            n += (v < 1.5f);
        }
    }
    __syncthreads();
    if (tid < 128) srt[rank] = myt;     // now sorted
    if (tid == 0) nInS = n;
    __syncthreads();
    const int nIn = nInS;

    if (bid == 385) {
        if (tid < 128) {
            W1w_f[tid] = w1s[tid];
            W1b_f[tid] = b1s[tid];
            W3b_f[tid] = loadF(W3b, tid, isB);
            W4b_f[tid] = loadF(W4b, tid, isB);
        }
        if (tid == 0) { *flag = isB; *iflag = i64; }
        return;
    }

    if (bid < 385) {
        // ab3 blocks: one j per block; j = bid-256 in [0,128], h = tid (<128)
        const int j = bid - 256;
        const int h = tid;
        if (tid < 128 && j <= nIn) {
            float left  = (j == 0)   ? 0.0f : srt[j - 1];
            float right = (j == nIn) ? 1.0f : srt[j];
            float mid = 0.5f * (left + right);
            float a = 0.0f, b = 0.0f;
            for (int k = 0; k < 128; ++k) {
                if (fmaf(mid, w1s[k], b1s[k]) > 0.0f) {
                    float w3 = loadF(W3w, h * 384 + k, isB);
                    a = fmaf(w1s[k], w3, a);
                    b = fmaf(b1s[k], w3, b);
                }
            }
            ab3p[j * 128 + h] = (unsigned int)f2bu(a)
                              | ((unsigned int)f2bu(b) << 16);
        }
        return;
    }

    // Edge-meta + starts-scatter pass: bid in [386, 642), 1024 edges/block.
    const int eb = (bid - 386) * 1024;
    #pragma unroll
    for (int r = 0; r < 4; ++r) {
        int i = eb + r * 256 + tid;
        int ent = loadI(nbr_ent, i, i64);
        int rel = loadI(nbr_rel, i, i64);
        float att = loadF(att_raw, i, isB);
        int lo = 0, hi = nIn;   // bucket = #breakpoints <= att
        while (lo < hi) {
            int m = (lo + hi) >> 1;
            if (srt[m] <= att) lo = m + 1; else hi = m;
        }
        metaE[i] = make_uint4(__float_as_uint(att),
                              (unsigned int)(ent << 7),
                              (unsigned int)(rel << 7),
                              (unsigned int)(lo << 7));

        // starts scatter: starts[t] = i for t in (seg_ids[i-1], seg_ids[i]]
        int cur = loadI(seg_ids, i, i64);
        int prev = (i == 0) ? -1 : loadI(seg_ids, i - 1, i64);
        for (int t = prev + 1; t <= cur; ++t) starts[t] = i;
        if (i == E_EDGES - 1) {
            for (int t = cur + 1; t <= T_SEG; ++t) starts[t] = E_EDGES;
        }
    }
}

// ---------------------------------------------------------------------------
// K_B: 32-row tiles, 128-thr blocks. (unchanged from r12)
// ---------------------------------------------------------------------------
#define KB_ENT_BLOCKS (N_ENT_C / 32)   // 1250
#define KB_REL_BLOCKS (N_REL_C / 32)   // 8

__global__ void __launch_bounds__(128)
kb_gemm(const void* __restrict__ ent_raw, const void* __restrict__ rel_raw,
        const int* __restrict__ flag,
        const unsigned short* __restrict__ wctEb,
        const unsigned short* __restrict__ wctRb,
        const float* __restrict__ W3b_f, const float* __restrict__ W4b_f,
        unsigned int* __restrict__ entp2, unsigned int* __restrict__ relp2)
{
    const int isB = *flag;
    const int bid = blockIdx.x, tid = threadIdx.x;

    const void* A; const unsigned short* WT; unsigned int* out; int m0, isRel;
    if (bid < KB_ENT_BLOCKS) {
        A = ent_raw; WT = wctEb; out = entp2; m0 = bid * 32; isRel = 0;
    } else {
        A = rel_raw; WT = wctRb; out = relp2;
        m0 = (bid - KB_ENT_BLOCKS) * 32; isRel = 1;
    }

    __shared__ unsigned short As[32][136];   // +8 pad: 272 B row, 16B-aligned

    if (isB) {
        for (int v = tid; v < 512; v += 128) {       // 512 short8, coalesced
            int e = v * 8, r = e >> 7, cc = e & 127;
            short8 x = *(const short8*)((const short*)A + m0 * 128 + e);
            *(short8*)&As[r][cc] = x;
        }
    } else {
        for (int v = tid; v < 1024; v += 128) {      // 1024 float4, coalesced
            int e = v * 4, r = e >> 7, cc = e & 127;
            float4 f = *(const float4*)((const float*)A + m0 * 128 + e);
            unsigned int lo = (unsigned int)f2bu(f.x) | ((unsigned int)f2bu(f.y) << 16);
            unsigned int hi = (unsigned int)f2bu(f.z) | ((unsigned int)f2bu(f.w) << 16);
            *(uint2*)&As[r][cc] = make_uint2(lo, hi);
        }
    }
    __syncthreads();

    const int wave = tid >> 6, lane = tid & 63;
    const int quad = lane >> 4, l16 = lane & 15;

    f32x4 acc3[8], acc4[8];
    #pragma unroll
    for (int np = 0; np < 8; ++np) {
        acc3[np] = (f32x4){0.f, 0.f, 0.f, 0.f};
        acc4[np] = (f32x4){0.f, 0.f, 0.f, 0.f};
    }

    #pragma unroll
    for (int kk = 0; kk < 4; ++kk) {
        const int kb = kk * 32 + quad * 8;
        short8 av = *(const short8*)&As[wave * 16 + l16][kb];
        #pragma unroll
        for (int np = 0; np < 8; ++np) {
            const short* bp = (const short*)WT + (np * 16 + l16) * 128 + kb;
            short8 bv3 = *(const short8*)bp;
            short8 bv4 = *(const short8*)(bp + 128 * 128);
            acc3[np] = __builtin_amdgcn_mfma_f32_16x16x32_bf16(av, bv3, acc3[np], 0, 0, 0);
            acc4[np] = __builtin_amdgcn_mfma_f32_16x16x32_bf16(av, bv4, acc4[np], 0, 0, 0);
        }
    }

    #pragma unroll
    for (int np = 0; np < 8; ++np) {
        int h = np * 16 + l16;
        float bias3 = isRel ? W3b_f[h] : 0.0f;
        float bias4 = isRel ? W4b_f[h] : 0.0f;
        #pragma unroll
        for (int r = 0; r < 4; ++r) {
            int m = m0 + wave * 16 + quad * 4 + r;
            unsigned int w = (unsigned int)f2bu(acc3[np][r] + bias3)
                           | ((unsigned int)f2bu(acc4[np][r] + bias4) << 16);
            out[m * 128 + h] = w;
        }
    }
}

// ---------------------------------------------------------------------------
// K_C v8 (unchanged from r16 — verified best at 173.04):
// 1 block/segment, 128 thr, 1 h/thread, unroll 8; scalar-pipe meta reads
// (uniform metaE[i] address, s/e via readfirstlane), no LDS, no barriers.
// ---------------------------------------------------------------------------
__global__ void __launch_bounds__(128)
kc_segment(const uint4* __restrict__ metaE,
           const int* __restrict__ starts,
           const unsigned int* __restrict__ entp2,
           const unsigned int* __restrict__ relp2,
           const unsigned int* __restrict__ ab3p,
           const void* __restrict__ sat_raw,
           const void* __restrict__ s_ids, const void* __restrict__ r_ids,
           const void* __restrict__ ent_raw, const void* __restrict__ rel_raw,
           const float* __restrict__ W1w_f, const float* __restrict__ W1b_f,
           const int* __restrict__ flag, const int* __restrict__ iflag,
           float* __restrict__ outS, float* __restrict__ outA)
{
    const int t = blockIdx.x, h = threadIdx.x;
    const int isB = *flag, i64 = *iflag;
    const int s = __builtin_amdgcn_readfirstlane(starts[t]);
    const int e = __builtin_amdgcn_readfirstlane(starts[t + 1]);

    // per-thread gather bases (offsets in metaE are element offsets)
    const unsigned int* __restrict__ entpH = entp2 + h;
    const unsigned int* __restrict__ relpH = relp2 + h;
    const unsigned int* __restrict__ ab3pH = ab3p + h;

    float acc3 = 0.0f, acc4 = 0.0f;

    #pragma unroll 8
    for (int i = s; i < e; ++i) {
        uint4 q = metaE[i];                       // uniform addr -> s_load
        float att = __uint_as_float(q.x);
        unsigned int ew = entpH[q.y];             // random L3 gather
        unsigned int rw = relpH[q.z];             // L2-hot (+biases)
        unsigned int aw = ab3pH[q.w];             // L2-hot, bf16-packed
        float p3s = __uint_as_float(ew << 16);
        float p4s = __uint_as_float(ew & 0xFFFF0000u);
        float p3r = __uint_as_float(rw << 16);
        float p4r = __uint_as_float(rw & 0xFFFF0000u);
        float a3  = __uint_as_float(aw << 16);
        float b3  = __uint_as_float(aw & 0xFFFF0000u);
        acc3 += fmaxf(fmaf(att, a3, b3) + p3s + p3r, 0.0f);
        acc4 += fmaxf(p4s + p4r, 0.0f);
    }

    const int cnt = e - s;
    const float inv = (cnt > 0) ? (1.0f / (float)cnt) : 1.0f;
    const int b = t / L_SEQ;
    const int sid = loadI(s_ids, b, i64);
    const int rid = loadI(r_ids, b, i64);
    const float se = loadF(ent_raw, sid * 128 + h, isB);
    const float sr = loadF(rel_raw, rid * 128 + h, isB);
    const float sa = loadF(sat_raw, t, isB);
    const float sae = fmaxf(fmaf(sa, W1w_f[h], W1b_f[h]), 0.0f);

    const size_t bs = (size_t)t * 384;
    outS[bs + h]       = se;
    outS[bs + 128 + h] = sr;
    outS[bs + 256 + h] = acc4 * inv;
    outA[bs + h]       = sae;
    outA[bs + 128 + h] = se;
    outA[bs + 256 + h] = acc3 * inv;
}

// ---------------------------------------------------------------------------
// Production config: ka x1, kb x1, kc x1.
// Attribution: tax ~124 (fixed), ka ~12, kb ~16.4, kc ~20.6 (r16=173.04 best).
// r17: ka starts-scatter (bitwise-identical starts, kills 41 binary-search
// blocks) + ab3 one-j-per-block (bitwise-identical ab3p, 2x parallelism).
// ---------------------------------------------------------------------------
extern "C" void kernel_launch(void* const* d_in, const int* in_sizes, int n_in,
                              void* d_out, int out_size, void* d_ws, size_t ws_size,
                              hipStream_t stream)
{
    const void* nbr_ent = d_in[0];
    const void* nbr_rel = d_in[1];
    const void* nbr_att = d_in[2];
    const void* seg_ids = d_in[3];
    const void* self_att = d_in[4];
    const void* s_ids = d_in[5];
    const void* r_ids = d_in[6];
    const void* ent_embeds = d_in[7];
    const void* rel_embeds = d_in[8];
    const void* W1w = d_in[9];
    const void* W1b = d_in[10];
    const void* W3w = d_in[11];
    const void* W3b = d_in[12];
    const void* W4w = d_in[13];
    const void* W4b = d_in[14];

    // workspace carve-up (~25.5 MB)
    char* ws = (char*)d_ws;
    size_t off = 0;
    auto alloc = [&](size_t bytes) -> void* {
        void* p = ws + off;
        off = (off + bytes + 255) & ~(size_t)255;
        return p;
    };
    int*   flag   = (int*)alloc(4);
    int*   iflag  = (int*)alloc(4);
    float* W1w_f  = (float*)alloc(128 * 4);
    float* W1b_f  = (float*)alloc(128 * 4);
    float* W3b_f  = (float*)alloc(128 * 4);
    float* W4b_f  = (float*)alloc(128 * 4);
    int*   starts = (int*)alloc((T_SEG + 1) * 4);
    unsigned short* wctEb = (unsigned short*)alloc(256 * 128 * 2);
    unsigned short* wctRb = (unsigned short*)alloc(256 * 128 * 2);
    unsigned int* ab3p = (unsigned int*)alloc(129 * 128 * 4);
    uint4* metaE = (uint4*)alloc((size_t)E_EDGES * 16);                   // 4 MB
    unsigned int* entp2 = (unsigned int*)alloc((size_t)N_ENT_C * 128 * 4); // 20.48 MB
    unsigned int* relp2 = (unsigned int*)alloc((size_t)N_REL_C * 128 * 4);

    float* outS = (float*)d_out;
    float* outA = outS + (size_t)T_SEG * 384;

    // K_A: all prep (wct tables + ab3p + starts-scatter + edge meta + scalars)
    ka_prep<<<642, 256, 0, stream>>>(W3w, W4w, W1w, W1b, W3b, W4b,
                                     seg_ids, nbr_ent, nbr_rel, nbr_att, s_ids,
                                     wctEb, wctRb, ab3p, starts, metaE,
                                     W1w_f, W1b_f, W3b_f, W4b_f,
                                     flag, iflag);

    // K_B: fused entity+relation MFMA projection GEMM (biases folded into rel)
    kb_gemm<<<KB_ENT_BLOCKS + KB_REL_BLOCKS, 128, 0, stream>>>(
        ent_embeds, rel_embeds, flag, wctEb, wctRb, W3b_f, W4b_f, entp2, relp2);

    // K_C: per-segment aggregation + epilogue (1 block/segment, 128 thr,
    //      scalar-pipe meta reads, no LDS, no barriers)
    kc_segment<<<T_SEG, 128, 0, stream>>>(
        metaE, starts, entp2, relp2, ab3p,
        self_att, s_ids, r_ids, ent_embeds, rel_embeds,
        W1w_f, W1b_f, flag, iflag, outS, outA);
}

// Round 19
// 172.784 us; speedup vs baseline: 1.0166x; 1.0166x over previous
//
#include <hip/hip_runtime.h>
#include <hip/hip_bf16.h>

// Problem constants (from reference)
#define E_EDGES 262144
#define B_SAMP  1024
#define L_SEQ   10
#define T_SEG   (B_SAMP * L_SEQ)   // 10240 segments
#define H_DIM   128
#define N_ENT_C 40000
#define N_REL_C 256

typedef __attribute__((ext_vector_type(8))) short short8;   // 8 bf16 (4 VGPRs)
typedef __attribute__((ext_vector_type(4))) float f32x4;

__device__ __forceinline__ float b2f(__hip_bfloat16 x) { return __bfloat162float(x); }
__device__ __forceinline__ unsigned short f2bu(float x) {
    return __bfloat16_as_ushort(__float2bfloat16(x));
}

// Float load with runtime-detected storage (bf16 vs float32).
__device__ __forceinline__ float loadF(const void* base, int idx, int isB16) {
    if (isB16) return b2f(((const __hip_bfloat16*)base)[idx]);
    return ((const float*)base)[idx];
}
// Integer load with runtime-detected width (int64 vs int32).
__device__ __forceinline__ int loadI(const void* base, int idx, int is64) {
    if (is64) return (int)(((const long long*)base)[idx]);
    return ((const int*)base)[idx];
}

// Per-block dtype detection (cheap, deterministic; no cross-block deps).
__device__ __forceinline__ void detect_dtypes(const void* att_raw,
                                              const void* sid_raw,
                                              int tid, int nthr,
                                              int& isB, int& i64)
{
    __shared__ int cF, cI;
    if (tid == 0) { cF = 0; cI = 0; }
    __syncthreads();
    const unsigned short* pa = (const unsigned short*)att_raw;
    int c = 0;
    for (int i = tid; i < 2048; i += nthr) if (pa[i] <= 0x3F80u) c++;
    if (c) atomicAdd(&cF, c);
    const int* ps = (const int*)sid_raw;
    c = 0;
    for (int i = tid; i < 512; i += nthr) if (ps[2 * i + 1] == 0) c++;
    if (c) atomicAdd(&cI, c);
    __syncthreads();
    isB = (cF >= 1900) ? 1 : 0;
    i64 = (cI >= 256) ? 1 : 0;
}

// ---------------------------------------------------------------------------
// K_A: all prep in one launch, blocks fully independent. (r16 layout — the
// verified best; r18's starts-scatter/ab3-split restructure measured +2.6us
// and was reverted: the binary-search blocks run concurrently with the 256
// table blocks and were never on the grid's critical path.)
//  bid [0,256):   bf16 weight tables, n-major k-contig for MFMA B-frags.
//  bid [256,321): ab3 — 2 j per block; ab3p[j][h] = packed {bf16 A3, bf16 B3}.
//  bid [321,362): segment start offsets via lower_bound on sorted seg_ids.
//  bid 362:       global scalar vectors + dtype flags.
//  bid [363,619): edge-meta pass. metaE[i] = uint4{att_f32_bits,
//                 ent*128, rel*128, j*128} (element offsets precomputed).
// ---------------------------------------------------------------------------
__global__ void __launch_bounds__(256)
ka_prep(const void* __restrict__ W3w, const void* __restrict__ W4w,
        const void* __restrict__ W1w, const void* __restrict__ W1b,
        const void* __restrict__ W3b, const void* __restrict__ W4b,
        const void* __restrict__ seg_ids,
        const void* __restrict__ nbr_ent, const void* __restrict__ nbr_rel,
        const void* __restrict__ att_raw, const void* __restrict__ sid_raw,
        unsigned short* __restrict__ wctEb, unsigned short* __restrict__ wctRb,
        unsigned int* __restrict__ ab3p, int* __restrict__ starts,
        uint4* __restrict__ metaE,
        float* __restrict__ W1w_f, float* __restrict__ W1b_f,
        float* __restrict__ W3b_f, float* __restrict__ W4b_f,
        int* __restrict__ flag, int* __restrict__ iflag)
{
    const int bid = blockIdx.x, tid = threadIdx.x;
    int isB, i64;
    detect_dtypes(att_raw, sid_raw, tid, 256, isB, i64);

    if (bid < 256) {
        int gid = bid * 256 + tid;
        if (gid < 32768) {
            int n = gid >> 7, k = gid & 127;
            float v = (n < 128) ? loadF(W3w, n * 384 + 128 + k, isB)
                                : loadF(W4w, (n - 128) * 256 + k, isB);
            wctEb[gid] = f2bu(v);
        } else {
            int j = gid - 32768;
            int n = j >> 7, k = j & 127;
            float v = (n < 128) ? loadF(W3w, n * 384 + 256 + k, isB)
                                : loadF(W4w, (n - 128) * 256 + 128 + k, isB);
            wctRb[j] = f2bu(v);
        }
        return;
    }

    if (bid >= 321 && bid <= 361) {
        // starts blocks: lower_bound on sorted seg_ids
        int t = (bid - 321) * 256 + tid;
        if (t <= T_SEG) {
            int lo = 0, hi = E_EDGES;
            while (lo < hi) {
                int m = (lo + hi) >> 1;
                if (loadI(seg_ids, m, i64) < t) lo = m + 1; else hi = m;
            }
            starts[t] = lo;
        }
        return;
    }

    // Remaining blocks all need the sorted breakpoints: derive locally.
    // thr_k = -b1k/w1k if in (0,1) else sentinel 2.0; rank-sort in LDS.
    __shared__ float w1s[128], b1s[128], srt[128];
    __shared__ int nInS;
    if (tid < 128) {
        float w = loadF(W1w, tid, isB);
        float b = loadF(W1b, tid, isB);
        w1s[tid] = w; b1s[tid] = b;
    }
    __syncthreads();
    if (tid < 128) {
        float w = w1s[tid], b = b1s[tid];
        float t = 2.0f;
        if (w != 0.0f) {
            float tt = -b / w;
            if (tt > 0.0f && tt < 1.0f) t = tt;
        }
        srt[tid] = t;   // temporarily unsorted
    }
    __syncthreads();
    float myt = 0.0f; int rank = 0, n = 0;
    if (tid < 128) {
        myt = srt[tid];
        for (int j = 0; j < 128; ++j) {
            float v = srt[j];
            rank += (v < myt) || (v == myt && j < tid);
            n += (v < 1.5f);
        }
    }
    __syncthreads();
    if (tid < 128) srt[rank] = myt;     // now sorted
    if (tid == 0) nInS = n;
    __syncthreads();
    const int nIn = nInS;

    if (bid == 362) {
        if (tid < 128) {
            W1w_f[tid] = w1s[tid];
            W1b_f[tid] = b1s[tid];
            W3b_f[tid] = loadF(W3b, tid, isB);
            W4b_f[tid] = loadF(W4b, tid, isB);
        }
        if (tid == 0) { *flag = isB; *iflag = i64; }
        return;
    }

    if (bid < 321) {
        // ab3 blocks: j = (bid-256)*2 + (tid>>7), h = tid&127
        const int j = (bid - 256) * 2 + (tid >> 7);
        const int h = tid & 127;
        if (j <= nIn) {
            float left  = (j == 0)   ? 0.0f : srt[j - 1];
            float right = (j == nIn) ? 1.0f : srt[j];
            float mid = 0.5f * (left + right);
            float a = 0.0f, b = 0.0f;
            for (int k = 0; k < 128; ++k) {
                if (fmaf(mid, w1s[k], b1s[k]) > 0.0f) {
                    float w3 = loadF(W3w, h * 384 + k, isB);
                    a = fmaf(w1s[k], w3, a);
                    b = fmaf(b1s[k], w3, b);
                }
            }
            ab3p[j * 128 + h] = (unsigned int)f2bu(a)
                              | ((unsigned int)f2bu(b) << 16);
        }
        return;
    }

    // Edge-meta pass: bid in [363, 619), 1024 edges per block.
    const int eb = (bid - 363) * 1024;
    #pragma unroll
    for (int r = 0; r < 4; ++r) {
        int i = eb + r * 256 + tid;
        int ent = loadI(nbr_ent, i, i64);
        int rel = loadI(nbr_rel, i, i64);
        float att = loadF(att_raw, i, isB);
        int lo = 0, hi = nIn;   // bucket = #breakpoints <= att
        while (lo < hi) {
            int m = (lo + hi) >> 1;
            if (srt[m] <= att) lo = m + 1; else hi = m;
        }
        metaE[i] = make_uint4(__float_as_uint(att),
                              (unsigned int)(ent << 7),
                              (unsigned int)(rel << 7),
                              (unsigned int)(lo << 7));
    }
}

// ---------------------------------------------------------------------------
// K_B: 32-row tiles, 128-thr blocks. (unchanged from r12/r16)
// ---------------------------------------------------------------------------
#define KB_ENT_BLOCKS (N_ENT_C / 32)   // 1250
#define KB_REL_BLOCKS (N_REL_C / 32)   // 8

__global__ void __launch_bounds__(128)
kb_gemm(const void* __restrict__ ent_raw, const void* __restrict__ rel_raw,
        const int* __restrict__ flag,
        const unsigned short* __restrict__ wctEb,
        const unsigned short* __restrict__ wctRb,
        const float* __restrict__ W3b_f, const float* __restrict__ W4b_f,
        unsigned int* __restrict__ entp2, unsigned int* __restrict__ relp2)
{
    const int isB = *flag;
    const int bid = blockIdx.x, tid = threadIdx.x;

    const void* A; const unsigned short* WT; unsigned int* out; int m0, isRel;
    if (bid < KB_ENT_BLOCKS) {
        A = ent_raw; WT = wctEb; out = entp2; m0 = bid * 32; isRel = 0;
    } else {
        A = rel_raw; WT = wctRb; out = relp2;
        m0 = (bid - KB_ENT_BLOCKS) * 32; isRel = 1;
    }

    __shared__ unsigned short As[32][136];   // +8 pad: 272 B row, 16B-aligned

    if (isB) {
        for (int v = tid; v < 512; v += 128) {       // 512 short8, coalesced
            int e = v * 8, r = e >> 7, cc = e & 127;
            short8 x = *(const short8*)((const short*)A + m0 * 128 + e);
            *(short8*)&As[r][cc] = x;
        }
    } else {
        for (int v = tid; v < 1024; v += 128) {      // 1024 float4, coalesced
            int e = v * 4, r = e >> 7, cc = e & 127;
            float4 f = *(const float4*)((const float*)A + m0 * 128 + e);
            unsigned int lo = (unsigned int)f2bu(f.x) | ((unsigned int)f2bu(f.y) << 16);
            unsigned int hi = (unsigned int)f2bu(f.z) | ((unsigned int)f2bu(f.w) << 16);
            *(uint2*)&As[r][cc] = make_uint2(lo, hi);
        }
    }
    __syncthreads();

    const int wave = tid >> 6, lane = tid & 63;
    const int quad = lane >> 4, l16 = lane & 15;

    f32x4 acc3[8], acc4[8];
    #pragma unroll
    for (int np = 0; np < 8; ++np) {
        acc3[np] = (f32x4){0.f, 0.f, 0.f, 0.f};
        acc4[np] = (f32x4){0.f, 0.f, 0.f, 0.f};
    }

    #pragma unroll
    for (int kk = 0; kk < 4; ++kk) {
        const int kb = kk * 32 + quad * 8;
        short8 av = *(const short8*)&As[wave * 16 + l16][kb];
        #pragma unroll
        for (int np = 0; np < 8; ++np) {
            const short* bp = (const short*)WT + (np * 16 + l16) * 128 + kb;
            short8 bv3 = *(const short8*)bp;
            short8 bv4 = *(const short8*)(bp + 128 * 128);
            acc3[np] = __builtin_amdgcn_mfma_f32_16x16x32_bf16(av, bv3, acc3[np], 0, 0, 0);
            acc4[np] = __builtin_amdgcn_mfma_f32_16x16x32_bf16(av, bv4, acc4[np], 0, 0, 0);
        }
    }

    #pragma unroll
    for (int np = 0; np < 8; ++np) {
        int h = np * 16 + l16;
        float bias3 = isRel ? W3b_f[h] : 0.0f;
        float bias4 = isRel ? W4b_f[h] : 0.0f;
        #pragma unroll
        for (int r = 0; r < 4; ++r) {
            int m = m0 + wave * 16 + quad * 4 + r;
            unsigned int w = (unsigned int)f2bu(acc3[np][r] + bias3)
                           | ((unsigned int)f2bu(acc4[np][r] + bias4) << 16);
            out[m * 128 + h] = w;
        }
    }
}

// ---------------------------------------------------------------------------
// K_C v8 (verified best at 173.04 in r16):
// 1 block/segment, 128 thr, 1 h/thread, unroll 8; scalar-pipe meta reads
// (uniform metaE[i] address, s/e via readfirstlane), no LDS, no barriers.
// ---------------------------------------------------------------------------
__global__ void __launch_bounds__(128)
kc_segment(const uint4* __restrict__ metaE,
           const int* __restrict__ starts,
           const unsigned int* __restrict__ entp2,
           const unsigned int* __restrict__ relp2,
           const unsigned int* __restrict__ ab3p,
           const void* __restrict__ sat_raw,
           const void* __restrict__ s_ids, const void* __restrict__ r_ids,
           const void* __restrict__ ent_raw, const void* __restrict__ rel_raw,
           const float* __restrict__ W1w_f, const float* __restrict__ W1b_f,
           const int* __restrict__ flag, const int* __restrict__ iflag,
           float* __restrict__ outS, float* __restrict__ outA)
{
    const int t = blockIdx.x, h = threadIdx.x;
    const int isB = *flag, i64 = *iflag;
    const int s = __builtin_amdgcn_readfirstlane(starts[t]);
    const int e = __builtin_amdgcn_readfirstlane(starts[t + 1]);

    // per-thread gather bases (offsets in metaE are element offsets)
    const unsigned int* __restrict__ entpH = entp2 + h;
    const unsigned int* __restrict__ relpH = relp2 + h;
    const unsigned int* __restrict__ ab3pH = ab3p + h;

    float acc3 = 0.0f, acc4 = 0.0f;

    #pragma unroll 8
    for (int i = s; i < e; ++i) {
        uint4 q = metaE[i];                       // uniform addr -> s_load
        float att = __uint_as_float(q.x);
        unsigned int ew = entpH[q.y];             // random L3 gather
        unsigned int rw = relpH[q.z];             // L2-hot (+biases)
        unsigned int aw = ab3pH[q.w];             // L2-hot, bf16-packed
        float p3s = __uint_as_float(ew << 16);
        float p4s = __uint_as_float(ew & 0xFFFF0000u);
        float p3r = __uint_as_float(rw << 16);
        float p4r = __uint_as_float(rw & 0xFFFF0000u);
        float a3  = __uint_as_float(aw << 16);
        float b3  = __uint_as_float(aw & 0xFFFF0000u);
        acc3 += fmaxf(fmaf(att, a3, b3) + p3s + p3r, 0.0f);
        acc4 += fmaxf(p4s + p4r, 0.0f);
    }

    const int cnt = e - s;
    const float inv = (cnt > 0) ? (1.0f / (float)cnt) : 1.0f;
    const int b = t / L_SEQ;
    const int sid = loadI(s_ids, b, i64);
    const int rid = loadI(r_ids, b, i64);
    const float se = loadF(ent_raw, sid * 128 + h, isB);
    const float sr = loadF(rel_raw, rid * 128 + h, isB);
    const float sa = loadF(sat_raw, t, isB);
    const float sae = fmaxf(fmaf(sa, W1w_f[h], W1b_f[h]), 0.0f);

    const size_t bs = (size_t)t * 384;
    outS[bs + h]       = se;
    outS[bs + 128 + h] = sr;
    outS[bs + 256 + h] = acc4 * inv;
    outA[bs + h]       = sae;
    outA[bs + 128 + h] = se;
    outA[bs + 256 + h] = acc3 * inv;
}

// ---------------------------------------------------------------------------
// Production config: ka x1, kb x1, kc x1. Exact r16 source (verified best,
// 173.04us). r18's ka restructure measured +2.6us and is reverted.
// Attribution: tax ~124 (fixed harness overhead), ka ~12, kb ~16, kc ~21.
// ---------------------------------------------------------------------------
extern "C" void kernel_launch(void* const* d_in, const int* in_sizes, int n_in,
                              void* d_out, int out_size, void* d_ws, size_t ws_size,
                              hipStream_t stream)
{
    const void* nbr_ent = d_in[0];
    const void* nbr_rel = d_in[1];
    const void* nbr_att = d_in[2];
    const void* seg_ids = d_in[3];
    const void* self_att = d_in[4];
    const void* s_ids = d_in[5];
    const void* r_ids = d_in[6];
    const void* ent_embeds = d_in[7];
    const void* rel_embeds = d_in[8];
    const void* W1w = d_in[9];
    const void* W1b = d_in[10];
    const void* W3w = d_in[11];
    const void* W3b = d_in[12];
    const void* W4w = d_in[13];
    const void* W4b = d_in[14];

    // workspace carve-up (~25.5 MB)
    char* ws = (char*)d_ws;
    size_t off = 0;
    auto alloc = [&](size_t bytes) -> void* {
        void* p = ws + off;
        off = (off + bytes + 255) & ~(size_t)255;
        return p;
    };
    int*   flag   = (int*)alloc(4);
    int*   iflag  = (int*)alloc(4);
    float* W1w_f  = (float*)alloc(128 * 4);
    float* W1b_f  = (float*)alloc(128 * 4);
    float* W3b_f  = (float*)alloc(128 * 4);
    float* W4b_f  = (float*)alloc(128 * 4);
    int*   starts = (int*)alloc((T_SEG + 1) * 4);
    unsigned short* wctEb = (unsigned short*)alloc(256 * 128 * 2);
    unsigned short* wctRb = (unsigned short*)alloc(256 * 128 * 2);
    unsigned int* ab3p = (unsigned int*)alloc(129 * 128 * 4);
    uint4* metaE = (uint4*)alloc((size_t)E_EDGES * 16);                   // 4 MB
    unsigned int* entp2 = (unsigned int*)alloc((size_t)N_ENT_C * 128 * 4); // 20.48 MB
    unsigned int* relp2 = (unsigned int*)alloc((size_t)N_REL_C * 128 * 4);

    float* outS = (float*)d_out;
    float* outA = outS + (size_t)T_SEG * 384;

    // K_A: all prep (wct tables + ab3p + starts + edge meta offsets + scalars)
    ka_prep<<<619, 256, 0, stream>>>(W3w, W4w, W1w, W1b, W3b, W4b,
                                     seg_ids, nbr_ent, nbr_rel, nbr_att, s_ids,
                                     wctEb, wctRb, ab3p, starts, metaE,
                                     W1w_f, W1b_f, W3b_f, W4b_f,
                                     flag, iflag);

    // K_B: fused entity+relation MFMA projection GEMM (biases folded into rel)
    kb_gemm<<<KB_ENT_BLOCKS + KB_REL_BLOCKS, 128, 0, stream>>>(
        ent_embeds, rel_embeds, flag, wctEb, wctRb, W3b_f, W4b_f, entp2, relp2);

    // K_C: per-segment aggregation + epilogue (1 block/segment, 128 thr,
    //      scalar-pipe meta reads, no LDS, no barriers)
    kc_segment<<<T_SEG, 128, 0, stream>>>(
        metaE, starts, entp2, relp2, ab3p,
        self_att, s_ids, r_ids, ent_embeds, rel_embeds,
        W1w_f, W1b_f, flag, iflag, outS, outA);
}